// Round 2
// baseline (696.856 us; speedup 1.0000x reference)
//
#include <hip/hip_runtime.h>
#include <hip/hip_bf16.h>

// word_choser: algebraically reduced. ALL float tensors are FLOAT32 (per the
// reference dtypes) — early rounds failed with NaN when f32 buffers were read
// as bf16.
//
//  t = colsum(hiddens)                       [D]
//  m = (t @ dim_up + cur_h) / (S+1)          [D]   (mean over node embs)
//  v = relu(m @ W_gcn)                       [D]   (all GCN rows identical)
//  softmax over identical scores is uniform -> att_result = v (att_w dead)
//  g = v @ dim_down                          [D]
//  gates[r] = Wi[r][0:D]·sen + Wi[r][D:2D]·g + Wi[r][2D]*pos + bi + Wh[r]·cur_h + bh
//  new_h = o * tanh(f*cur_cell + i*tanh(g_gate))   [D]
//  out = new_h @ dim_out                     [NTOK]
//
// DETERMINISM: the harness's post-timing tripwire requires bit-identical
// output on every graph replay. Round-1 failed it because the matvec stages
// used float atomicAdd (64 adds/element in scheduler-dependent order). All
// reductions are now two-phase with exclusively-owned partial slots summed in
// a fixed order — no atomics anywhere in the chain.

#define DD    2048
#define NTOK  32000
#define INPD  4097
#define INV_N (1.0f/4097.0f)

// ws layout (floats), total 75776 floats = 296 KiB (ws is ~1 GB per the
// harness's poison-fill size).
#define WS_PT 0        // [8][2048] colsum(hiddens) partials
#define WS_GB 16384    // [8192]    gate_base
#define WS_PM 24576    // [8][2048] (t@dim_up) partials
#define WS_PV 40960    // [8][2048] (m@W_gcn) partials
#define WS_PG 57344    // [8][2048] (v@dim_down) partials
#define WS_NH 73728    // [2048]    new_h

// K1: blocks 0..255: gate_base rows (Wi first half + Wh + bias + pos term)
//     blocks 256..319: column-sum partials of hiddens (one writer per slot)
// Wh/cur_h dot uses ds_read_b128 (lane*16B) — conflict-free LDS pattern.
__global__ __launch_bounds__(256) void k1_base(
    const float* __restrict__ sen, const float* __restrict__ hid,
    const int* __restrict__ posp,
    const float* __restrict__ Wi, const float* __restrict__ Wh,
    const float* __restrict__ bi, const float* __restrict__ bh,
    const float* __restrict__ curh, float* __restrict__ ws)
{
    __shared__ float sen_lds[DD];
    __shared__ __align__(16) float ch_lds[DD];
    const int t = threadIdx.x;
    const int b = blockIdx.x;
    const int wv = t >> 6, lane = t & 63;
    if (b < 256) {
        for (int k = 0; k < 8; ++k) {
            int idx = t + k*256;
            sen_lds[idx] = sen[idx];
            ch_lds[idx]  = curh[idx];
        }
        __syncthreads();
        float posf = (float)(*posp);
        const float4* ch4 = (const float4*)ch_lds;
        for (int i = 0; i < 8; ++i) {
            int r = b*32 + wv*8 + i;                 // r = gate*2048 + d
            const float*  wir = Wi + (size_t)r * INPD;        // 4B aligned only
            const float4* whr = (const float4*)(Wh + (size_t)r * DD); // 16B aligned
            float acc = 0.f;
            #pragma unroll
            for (int k = 0; k < 32; ++k) {
                int c = k*64 + lane;
                acc += wir[c] * sen_lds[c];
            }
            #pragma unroll
            for (int k = 0; k < 8; ++k) {
                float4 q  = whr[k*64 + lane];
                float4 cv = ch4[k*64 + lane];        // ds_read_b128, conflict-free
                acc += q.x*cv.x + q.y*cv.y + q.z*cv.z + q.w*cv.w;
            }
            if (lane == 0)
                acc += posf * wir[4096] + bi[r] + bh[r];
            #pragma unroll
            for (int off = 32; off > 0; off >>= 1) acc += __shfl_down(acc, off, 64);
            if (lane == 0) ws[WS_GB + r] = acc;
        }
    } else {
        int ww = (b - 256)*4 + wv;                   // 256 wave tasks
        int dg = ww & 31, rc = ww >> 5;
        int d = dg*64 + lane;
        const float* hp = hid + (size_t)(rc*512) * DD + d;
        float acc = 0.f;
        #pragma unroll 16
        for (int k = 0; k < 512; ++k) acc += hp[(size_t)k * DD];
        ws[WS_PT + rc*2048 + d] = acc;
    }
}

// K2/K3/K4: deterministic y = x @ M (M row-major DxD f32), two-phase.
// 256 one-wave blocks: ic = b>>5 (row chunk of 256), jc = b&31 (64 cols).
// Each block serially accumulates its 256-row slab and writes the
// exclusively-owned partial slot partial[ic][jc*64+lane]; the consumer sums
// the 8 chunks in fixed order. No atomics -> bit-identical every replay.
// MODE 0: x = sum8(WS_PT)                  -> WS_PM
// MODE 1: x = (sum8(WS_PM)+curh)/N         -> WS_PV
// MODE 2: x = relu(sum8(WS_PV))            -> WS_PG
template<int MODE>
__global__ __launch_bounds__(64) void k_mv(const float* __restrict__ M,
                                           const float* __restrict__ curh,
                                           float* __restrict__ ws)
{
    __shared__ float x_lds[256];
    const int b = blockIdx.x;
    const int lane = threadIdx.x;
    const int ic = b >> 5;          // row chunk (256 rows)
    const int jc = b & 31;          // col group (64 cols)
    const int i0 = ic * 256;
    #pragma unroll
    for (int k = 0; k < 4; ++k) {
        int ii = lane + k*64;
        int i = i0 + ii;
        float xv;
        if (MODE == 0) {
            float s = 0.f;
            #pragma unroll
            for (int c = 0; c < 8; ++c) s += ws[WS_PT + c*2048 + i];
            xv = s;
        } else if (MODE == 1) {
            float s = 0.f;
            #pragma unroll
            for (int c = 0; c < 8; ++c) s += ws[WS_PM + c*2048 + i];
            xv = (s + curh[i]) * INV_N;
        } else {
            float s = 0.f;
            #pragma unroll
            for (int c = 0; c < 8; ++c) s += ws[WS_PV + c*2048 + i];
            xv = fmaxf(s, 0.f);
        }
        x_lds[ii] = xv;
    }
    __syncthreads();
    const int j = jc*64 + lane;
    const float* mp = M + (size_t)i0 * DD + j;
    float acc = 0.f;
    #pragma unroll 8
    for (int ii = 0; ii < 256; ++ii)
        acc += x_lds[ii] * mp[(size_t)ii * DD];
    const int dst = (MODE == 0 ? WS_PM : (MODE == 1 ? WS_PV : WS_PG));
    ws[dst + ic*2048 + j] = acc;
}

// K5: gate_mid = Wi[:, D:2D] . g ; combine with gate_base; LSTM cell -> new_h.
// g is reconstructed from the 8 WS_PG chunks in fixed order (deterministic).
// Block b: d-range [b*8, b*8+8), wave = gate index.
__global__ __launch_bounds__(256) void k5_gates(
    const float* __restrict__ Wi, const float* __restrict__ curc,
    float* __restrict__ ws)
{
    __shared__ float g_lds[DD];
    __shared__ float gsum[4][8];
    const int t = threadIdx.x, b = blockIdx.x;
    const int wv = t >> 6, lane = t & 63;
    for (int k = 0; k < 8; ++k) {
        int idx = t + k*256;
        float s = 0.f;
        #pragma unroll
        for (int c = 0; c < 8; ++c) s += ws[WS_PG + c*2048 + idx];
        g_lds[idx] = s;
    }
    __syncthreads();
    const int d0 = b * 8;
    for (int i = 0; i < 8; ++i) {
        int r = wv*2048 + d0 + i;
        const float* wir = Wi + (size_t)r * INPD + 2048;   // middle slab, 4B aligned
        float acc = 0.f;
        #pragma unroll
        for (int k = 0; k < 32; ++k) {
            int c = k*64 + lane;
            acc += wir[c] * g_lds[c];
        }
        #pragma unroll
        for (int off = 32; off > 0; off >>= 1) acc += __shfl_down(acc, off, 64);
        if (lane == 0) gsum[wv][i] = acc + ws[WS_GB + r];
    }
    __syncthreads();
    if (t < 8) {
        int d = d0 + t;
        float gi = 1.f/(1.f + __expf(-gsum[0][t]));
        float gf = 1.f/(1.f + __expf(-gsum[1][t]));
        float gg = tanhf(gsum[2][t]);
        float go = 1.f/(1.f + __expf(-gsum[3][t]));
        float nc = gf * curc[d] + gi * gg;
        ws[WS_NH + d] = go * tanhf(nc);
    }
}

// K6: out = new_h @ dim_out (262 MB f32). 250 blocks x 128 n's.
// Wave = d-chunk of 512. Row-pair lane split: lanes 0-31 take even rows,
// lanes 32-63 take odd rows; each lane reads float4 (16B) covering 4 n's.
__global__ __launch_bounds__(256) void k6_out(
    const float* __restrict__ Dout, const float* __restrict__ ws,
    float* __restrict__ out)
{
    __shared__ float h_lds[DD];
    __shared__ float4 red4[4][32];
    const int t = threadIdx.x, b = blockIdx.x;
    const int wv = t >> 6, lane = t & 63;
    const int half = lane >> 5;          // row parity
    const int cl   = lane & 31;          // column slot (4 n's each)
    for (int k = 0; k < 8; ++k) h_lds[t + k*256] = ws[WS_NH + t + k*256];
    __syncthreads();
    const int n0 = b * 128;
    float a0 = 0.f, a1 = 0.f, a2 = 0.f, a3 = 0.f;
    const float*  hp = h_lds + wv*512 + half;
    const float4* cp = (const float4*)(Dout + (size_t)(wv*512 + half) * NTOK + n0) + cl;
    #pragma unroll 8
    for (int k = 0; k < 256; ++k) {
        float4 q = cp[(size_t)k * 2 * (NTOK/4)];   // stride = 2 rows
        float h = hp[k*2];                          // broadcast within half
        a0 += h * q.x;
        a1 += h * q.y;
        a2 += h * q.z;
        a3 += h * q.w;
    }
    // combine row-pair halves: lanes 0-31 pick up lane+32's partials
    a0 += __shfl_down(a0, 32, 64);
    a1 += __shfl_down(a1, 32, 64);
    a2 += __shfl_down(a2, 32, 64);
    a3 += __shfl_down(a3, 32, 64);
    if (half == 0)
        red4[wv][cl] = make_float4(a0, a1, a2, a3);   // b128 store, conflict-free
    __syncthreads();
    if (t < 128) {
        const float* rf = (const float*)red4;
        out[n0 + t] = rf[t] + rf[128 + t] + rf[256 + t] + rf[384 + t];
    }
}

extern "C" void kernel_launch(void* const* d_in, const int* in_sizes, int n_in,
                              void* d_out, int out_size, void* d_ws, size_t ws_size,
                              hipStream_t stream)
{
    const float* sen  = (const float*)d_in[0];
    const float* hid  = (const float*)d_in[1];
    const int*   posp = (const int*)d_in[2];
    const float* dup  = (const float*)d_in[3];
    const float* ddn  = (const float*)d_in[4];
    const float* dout = (const float*)d_in[5];
    const float* wgcn = (const float*)d_in[6];
    // d_in[7] att_w: unused — softmax over identical scores is uniform.
    const float* Wi   = (const float*)d_in[8];
    const float* Wh   = (const float*)d_in[9];
    const float* bi   = (const float*)d_in[10];
    const float* bh   = (const float*)d_in[11];
    const float* curh = (const float*)d_in[12];
    const float* curc = (const float*)d_in[13];
    float* ws  = (float*)d_ws;
    float* out = (float*)d_out;

    k1_base<<<dim3(320), dim3(256), 0, stream>>>(sen, hid, posp, Wi, Wh, bi, bh, curh, ws);
    k_mv<0><<<dim3(256), dim3(64), 0, stream>>>(dup,  curh, ws);
    k_mv<1><<<dim3(256), dim3(64), 0, stream>>>(wgcn, curh, ws);
    k_mv<2><<<dim3(256), dim3(64), 0, stream>>>(ddn,  curh, ws);
    k5_gates<<<dim3(256), dim3(256), 0, stream>>>(Wi, curc, ws);
    k6_out<<<dim3(250), dim3(256), 0, stream>>>(dout, ws, out);
}